// Round 1
// baseline (256.847 us; speedup 1.0000x reference)
//
#include <hip/hip_runtime.h>

#define BATCH 2048
#define DIM   100000
#define STEPS 3125              // DIM / 32 (exact)
#define NSPLIT 16
#define WAVES_PER_BLOCK 4
#define NCHUNK (NSPLIT * WAVES_PER_BLOCK)   // 64
#define STEPS_PER_CHUNK 49      // ceil(3125/64); last chunk gets 38

typedef float f32x4  __attribute__((ext_vector_type(4)));
typedef short bf16x8 __attribute__((ext_vector_type(8)));

// round-to-nearest-even f32 -> bf16 bits
__device__ __forceinline__ short f2bf(float f) {
    unsigned u = __builtin_bit_cast(unsigned, f);
    u += 0x7FFFu + ((u >> 16) & 1u);
    return (short)(u >> 16);
}

// ---------------------------------------------------------------------------
// Kernel 1: pack B operands into MFMA fragment order (bf16).
// Layout: B[j][h][c][i], j = d/32, h = (d/8)&3, i = d&7, c = column 0..15.
// Bv columns = v[:,c].  Bc col0 = w, col1 = V2sum = sum_k v^2, rest 0.
// ---------------------------------------------------------------------------
__global__ void fm_pack(const float* __restrict__ w, const float* __restrict__ v,
                        short* __restrict__ Bv, short* __restrict__ Bc) {
    int d = blockIdx.x * blockDim.x + threadIdx.x;
    if (d >= DIM) return;
    int j = d >> 5, h = (d >> 3) & 3, i = d & 7;
    size_t base = (size_t)j * 512 + (size_t)h * 128 + i;   // + c*8
    float v2s = 0.f;
    #pragma unroll
    for (int c = 0; c < 16; ++c) {
        float vc = v[(size_t)d * 16 + c];
        v2s += vc * vc;
        Bv[base + c * 8] = f2bf(vc);
    }
    Bc[base + 0 * 8] = f2bf(w[d]);
    Bc[base + 1 * 8] = f2bf(v2s);
    #pragma unroll
    for (int c = 2; c < 16; ++c) Bc[base + c * 8] = 0;
}

// ---------------------------------------------------------------------------
// Kernel 2: main pass. Each wave: one 16-row tile x one K-chunk.
//   acc_s = x  @ Bv   (16 s_k columns)
//   acc_l = x  @ Bc   (col0 = linear term)
//   acc_q = x² @ Bc   (col1 = sum-of-squares term)
// Partials -> P[row][chunk][18] = {s_0..15, lin, ss}
// ---------------------------------------------------------------------------
__global__ __launch_bounds__(256, 4) void fm_main(
        const float* __restrict__ x,
        const short* __restrict__ Bv, const short* __restrict__ Bc,
        float* __restrict__ P) {
    int bid     = blockIdx.x;
    int split   = bid % NSPLIT;       // consecutive bids -> different XCDs;
    int rowtile = bid / NSPLIT;       // same split shares its B slice in L2
    int lane = threadIdx.x & 63;
    int wave = threadIdx.x >> 6;
    int chunk = split * WAVES_PER_BLOCK + wave;
    int s0 = chunk * STEPS_PER_CHUNK;
    int s1 = s0 + STEPS_PER_CHUNK; if (s1 > STEPS) s1 = STEPS;

    int c = lane & 15;                // A row / B col index
    int h = lane >> 4;                // k-group
    const float* xrow = x + (size_t)(rowtile * 16 + c) * DIM + h * 8;

    f32x4 acc_s = {0.f, 0.f, 0.f, 0.f};
    f32x4 acc_l = {0.f, 0.f, 0.f, 0.f};
    f32x4 acc_q = {0.f, 0.f, 0.f, 0.f};

    #pragma unroll 2
    for (int s = s0; s < s1; ++s) {
        const f32x4* xp = (const f32x4*)(xrow + (size_t)s * 32);
        f32x4 xa = xp[0];
        f32x4 xb = xp[1];
        bf16x8 bv = *(const bf16x8*)(Bv + (size_t)s * 512 + h * 128 + c * 8);
        bf16x8 bc = *(const bf16x8*)(Bc + (size_t)s * 512 + h * 128 + c * 8);
        bf16x8 a1, a2;
        #pragma unroll
        for (int i = 0; i < 4; ++i) {
            a1[i]     = f2bf(xa[i]);
            a1[i + 4] = f2bf(xb[i]);
            a2[i]     = f2bf(xa[i] * xa[i]);
            a2[i + 4] = f2bf(xb[i] * xb[i]);
        }
        acc_s = __builtin_amdgcn_mfma_f32_16x16x32_bf16(a1, bv, acc_s, 0, 0, 0);
        acc_l = __builtin_amdgcn_mfma_f32_16x16x32_bf16(a1, bc, acc_l, 0, 0, 0);
        acc_q = __builtin_amdgcn_mfma_f32_16x16x32_bf16(a2, bc, acc_q, 0, 0, 0);
    }

    // C/D layout: col = lane&15, row = (lane>>4)*4 + reg  [verified m89]
    #pragma unroll
    for (int r = 0; r < 4; ++r) {
        size_t row = (size_t)rowtile * 16 + h * 4 + r;
        float* Pp = P + (row * NCHUNK + chunk) * 18;
        Pp[c] = acc_s[r];
        if (c == 0) Pp[16] = acc_l[r];
        if (c == 1) Pp[17] = acc_q[r];
    }
}

// ---------------------------------------------------------------------------
// Kernel 3: reduce partials. out[b] = lin + 0.5*(sum_k s_k^2 - ss)
// ---------------------------------------------------------------------------
__global__ void fm_reduce(const float* __restrict__ P, float* __restrict__ out) {
    int b = blockIdx.x * blockDim.x + threadIdx.x;
    if (b >= BATCH) return;
    float sk[16];
    #pragma unroll
    for (int k = 0; k < 16; ++k) sk[k] = 0.f;
    float lin = 0.f, ss = 0.f;
    const float* Pb = P + (size_t)b * NCHUNK * 18;
    for (int ch = 0; ch < NCHUNK; ++ch) {
        const float* q = Pb + ch * 18;
        #pragma unroll
        for (int k = 0; k < 16; ++k) sk[k] += q[k];
        lin += q[16];
        ss  += q[17];
    }
    float acc = lin - 0.5f * ss;
    #pragma unroll
    for (int k = 0; k < 16; ++k) acc += 0.5f * sk[k] * sk[k];
    out[b] = acc;
}

// ---------------------------------------------------------------------------
extern "C" void kernel_launch(void* const* d_in, const int* in_sizes, int n_in,
                              void* d_out, int out_size, void* d_ws, size_t ws_size,
                              hipStream_t stream) {
    const float* x = (const float*)d_in[0];   // [2048, 100000]
    const float* w = (const float*)d_in[1];   // [100000, 1]
    const float* v = (const float*)d_in[2];   // [100000, 16]
    float* out = (float*)d_out;               // [2048]

    // workspace layout
    char* ws = (char*)d_ws;
    short* Bv = (short*)(ws);                        // 100000*16*2 = 3.2 MB
    short* Bc = (short*)(ws + 3200000);              // 3.2 MB
    float* P  = (float*)(ws + 6400000);              // 2048*64*18*4 = 9.44 MB

    fm_pack<<<(DIM + 255) / 256, 256, 0, stream>>>(w, v, Bv, Bc);
    fm_main<<<128 * NSPLIT, 256, 0, stream>>>(x, Bv, Bc, P);
    fm_reduce<<<(BATCH + 255) / 256, 256, 0, stream>>>(P, out);
}

// Round 2
// 238.608 us; speedup vs baseline: 1.0764x; 1.0764x over previous
//
#include <hip/hip_runtime.h>
#include <hip/hip_bf16.h>

#define BATCH 2048
#define DIM   100000
#define STEPS 3125              // DIM / 32 (exact)
#define NSPLIT 16
#define WAVES_PER_BLOCK 4
#define NCHUNK (NSPLIT * WAVES_PER_BLOCK)   // 64
#define STEPS_PER_CHUNK 49      // ceil(3125/64); last chunk gets 38

typedef float f32x4  __attribute__((ext_vector_type(4)));
typedef short bf16x8 __attribute__((ext_vector_type(8)));

// f32 -> bf16 bits via HW convert (compiler pairs these into v_cvt_pk_bf16_f32)
__device__ __forceinline__ short f2bf(float f) {
    return (short)__builtin_bit_cast(unsigned short, __float2bfloat16(f));
}

// ---------------------------------------------------------------------------
// Kernel 1: pack B operands into MFMA fragment order (bf16).
// Layout: B[j][h][c][i], j = d/32, h = (d/8)&3, i = d&7, c = column 0..15.
// One thread per (j,h): handles 8 consecutive d, writes 16B-vector stores.
// Bv columns = v[:,c].  Bc col0 = w, col1 = V2sum = sum_k v^2, rest 0.
// ---------------------------------------------------------------------------
__global__ void fm_pack(const float* __restrict__ w, const float* __restrict__ v,
                        short* __restrict__ Bv, short* __restrict__ Bc) {
    int t = blockIdx.x * blockDim.x + threadIdx.x;
    if (t >= STEPS * 4) return;
    int j = t >> 2, h = t & 3;
    int d0 = j * 32 + h * 8;
    size_t base = (size_t)j * 512 + (size_t)h * 128;

    short bv[16][8];
    float v2s[8];
    short wbits[8];
    #pragma unroll
    for (int i = 0; i < 8; ++i) {
        const f32x4* vp = (const f32x4*)(v + (size_t)(d0 + i) * 16);
        f32x4 r0 = vp[0], r1 = vp[1], r2 = vp[2], r3 = vp[3];
        float s = 0.f;
        #pragma unroll
        for (int q = 0; q < 4; ++q) {
            s += r0[q]*r0[q] + r1[q]*r1[q] + r2[q]*r2[q] + r3[q]*r3[q];
            bv[q + 0][i]  = f2bf(r0[q]);
            bv[q + 4][i]  = f2bf(r1[q]);
            bv[q + 8][i]  = f2bf(r2[q]);
            bv[q + 12][i] = f2bf(r3[q]);
        }
        v2s[i] = s;
        wbits[i] = f2bf(w[d0 + i]);
    }

    #pragma unroll
    for (int c = 0; c < 16; ++c) {
        bf16x8 o;
        #pragma unroll
        for (int i = 0; i < 8; ++i) o[i] = bv[c][i];
        *(bf16x8*)(Bv + base + c * 8) = o;
    }
    bf16x8 z = (bf16x8)0;
    bf16x8 c0, c1;
    #pragma unroll
    for (int i = 0; i < 8; ++i) { c0[i] = wbits[i]; c1[i] = f2bf(v2s[i]); }
    *(bf16x8*)(Bc + base + 0) = c0;
    *(bf16x8*)(Bc + base + 8) = c1;
    #pragma unroll
    for (int c = 2; c < 16; ++c) *(bf16x8*)(Bc + base + c * 8) = z;
}

// ---------------------------------------------------------------------------
// Kernel 2: main pass. Each wave: one 16-row tile x one K-chunk.
//   acc_s = x  @ Bv   (16 s_k columns)
//   acc_l = x  @ Bc   (col0 = linear term)
//   acc_q = x² @ Bc   (col1 = sum-of-squares term)
// Partials -> P[row][chunk][18] = {s_0..15, lin, ss}
// ---------------------------------------------------------------------------
__global__ __launch_bounds__(256, 4) void fm_main(
        const float* __restrict__ x,
        const short* __restrict__ Bv, const short* __restrict__ Bc,
        float* __restrict__ P) {
    int bid     = blockIdx.x;
    int split   = bid % NSPLIT;       // consecutive bids -> different XCDs;
    int rowtile = bid / NSPLIT;       // same split shares its B slice in L2
    int lane = threadIdx.x & 63;
    int wave = threadIdx.x >> 6;
    int chunk = split * WAVES_PER_BLOCK + wave;
    int s0 = chunk * STEPS_PER_CHUNK;
    int s1 = s0 + STEPS_PER_CHUNK; if (s1 > STEPS) s1 = STEPS;

    int c = lane & 15;                // A row / B col index
    int h = lane >> 4;                // k-group
    const float* xrow = x + (size_t)(rowtile * 16 + c) * DIM + h * 8;

    f32x4 acc_s = {0.f, 0.f, 0.f, 0.f};
    f32x4 acc_l = {0.f, 0.f, 0.f, 0.f};
    f32x4 acc_q = {0.f, 0.f, 0.f, 0.f};

    #pragma unroll 2
    for (int s = s0; s < s1; ++s) {
        const f32x4* xp = (const f32x4*)(xrow + (size_t)s * 32);
        f32x4 xa = __builtin_nontemporal_load(xp);      // x streamed once:
        f32x4 xb = __builtin_nontemporal_load(xp + 1);  // don't pollute L2
        bf16x8 bv = *(const bf16x8*)(Bv + (size_t)s * 512 + h * 128 + c * 8);
        bf16x8 bc = *(const bf16x8*)(Bc + (size_t)s * 512 + h * 128 + c * 8);
        bf16x8 a1, a2;
        #pragma unroll
        for (int i = 0; i < 4; ++i) {
            a1[i]     = f2bf(xa[i]);
            a1[i + 4] = f2bf(xb[i]);
            a2[i]     = f2bf(xa[i] * xa[i]);
            a2[i + 4] = f2bf(xb[i] * xb[i]);
        }
        acc_s = __builtin_amdgcn_mfma_f32_16x16x32_bf16(a1, bv, acc_s, 0, 0, 0);
        acc_l = __builtin_amdgcn_mfma_f32_16x16x32_bf16(a1, bc, acc_l, 0, 0, 0);
        acc_q = __builtin_amdgcn_mfma_f32_16x16x32_bf16(a2, bc, acc_q, 0, 0, 0);
    }

    // C/D layout: col = lane&15, row = (lane>>4)*4 + reg  [verified m89]
    #pragma unroll
    for (int r = 0; r < 4; ++r) {
        size_t row = (size_t)rowtile * 16 + h * 4 + r;
        float* Pp = P + (row * NCHUNK + chunk) * 18;
        Pp[c] = acc_s[r];
        if (c == 0) Pp[16] = acc_l[r];
        if (c == 1) Pp[17] = acc_q[r];
    }
}

// ---------------------------------------------------------------------------
// Kernel 3: reduce partials. One wave per batch row; lane = chunk.
// out[b] = lin + 0.5*(sum_k s_k^2 - ss)
// ---------------------------------------------------------------------------
__global__ __launch_bounds__(64) void fm_reduce(const float* __restrict__ P,
                                                float* __restrict__ out) {
    int b = blockIdx.x;
    int lane = threadIdx.x;           // 0..63 == chunk index
    const float* q = P + ((size_t)b * NCHUNK + lane) * 18;
    float r[18];
    #pragma unroll
    for (int i = 0; i < 18; ++i) r[i] = q[i];
    #pragma unroll
    for (int off = 32; off > 0; off >>= 1) {
        #pragma unroll
        for (int i = 0; i < 18; ++i) r[i] += __shfl_xor(r[i], off, 64);
    }
    if (lane == 0) {
        float acc = r[16] - 0.5f * r[17];
        #pragma unroll
        for (int k = 0; k < 16; ++k) acc += 0.5f * r[k] * r[k];
        out[b] = acc;
    }
}

// ---------------------------------------------------------------------------
extern "C" void kernel_launch(void* const* d_in, const int* in_sizes, int n_in,
                              void* d_out, int out_size, void* d_ws, size_t ws_size,
                              hipStream_t stream) {
    const float* x = (const float*)d_in[0];   // [2048, 100000]
    const float* w = (const float*)d_in[1];   // [100000, 1]
    const float* v = (const float*)d_in[2];   // [100000, 16]
    float* out = (float*)d_out;               // [2048]

    // workspace layout
    char* ws = (char*)d_ws;
    short* Bv = (short*)(ws);                        // 100000*16*2 = 3.2 MB
    short* Bc = (short*)(ws + 3200000);              // 3.2 MB
    float* P  = (float*)(ws + 6400000);              // 2048*64*18*4 = 9.44 MB

    fm_pack<<<(STEPS * 4 + 255) / 256, 256, 0, stream>>>(w, v, Bv, Bc);
    fm_main<<<128 * NSPLIT, 256, 0, stream>>>(x, Bv, Bc, P);
    fm_reduce<<<BATCH, 64, 0, stream>>>(P, out);
}

// Round 3
// 190.944 us; speedup vs baseline: 1.3451x; 1.2496x over previous
//
#include <hip/hip_runtime.h>
#include <hip/hip_bf16.h>

#define BATCH 2048
#define DIM   100000
#define STEPS 3125              // DIM / 32 (exact)
#define NSPLIT 25               // column splits; 100000/25 = 4000 = 15*256 + 160
#define COLS_PER_SPLIT 4000
#define NTILES 16               // 15 full tiles of 256 + 1 tail tile of 160
#define ROWTILES 128            // 2048 / 16

typedef float f32x4  __attribute__((ext_vector_type(4)));
typedef short bf16x8 __attribute__((ext_vector_type(8)));

// f32 -> bf16 bits via HW convert (compiler pairs into v_cvt_pk_bf16_f32)
__device__ __forceinline__ short f2bf(float f) {
    return (short)__builtin_bit_cast(unsigned short, __float2bfloat16(f));
}

// ---------------------------------------------------------------------------
// Kernel 1: pack B operands into MFMA fragment order (bf16).
// Layout: B[j][h][c][i], j = d/32, h = (d/8)&3, i = d&7, c = column 0..15.
// One thread per (j,h): handles 8 consecutive d, 16B-vector stores.
// Bv columns = v[:,c].  Bc col0 = w, col1 = V2sum = sum_k v^2, rest 0.
// ---------------------------------------------------------------------------
__global__ void fm_pack(const float* __restrict__ w, const float* __restrict__ v,
                        short* __restrict__ Bv, short* __restrict__ Bc) {
    int t = blockIdx.x * blockDim.x + threadIdx.x;
    if (t >= STEPS * 4) return;
    int j = t >> 2, h = t & 3;
    int d0 = j * 32 + h * 8;
    size_t base = (size_t)j * 512 + (size_t)h * 128;

    short bv[16][8];
    float v2s[8];
    short wbits[8];
    #pragma unroll
    for (int i = 0; i < 8; ++i) {
        const f32x4* vp = (const f32x4*)(v + (size_t)(d0 + i) * 16);
        f32x4 r0 = vp[0], r1 = vp[1], r2 = vp[2], r3 = vp[3];
        float s = 0.f;
        #pragma unroll
        for (int q = 0; q < 4; ++q) {
            s += r0[q]*r0[q] + r1[q]*r1[q] + r2[q]*r2[q] + r3[q]*r3[q];
            bv[q + 0][i]  = f2bf(r0[q]);
            bv[q + 4][i]  = f2bf(r1[q]);
            bv[q + 8][i]  = f2bf(r2[q]);
            bv[q + 12][i] = f2bf(r3[q]);
        }
        v2s[i] = s;
        wbits[i] = f2bf(w[d0 + i]);
    }
    #pragma unroll
    for (int c = 0; c < 16; ++c) {
        bf16x8 o;
        #pragma unroll
        for (int i = 0; i < 8; ++i) o[i] = bv[c][i];
        *(bf16x8*)(Bv + base + c * 8) = o;
    }
    bf16x8 z = (bf16x8)0;
    bf16x8 c0, c1;
    #pragma unroll
    for (int i = 0; i < 8; ++i) { c0[i] = wbits[i]; c1[i] = f2bf(v2s[i]); }
    *(bf16x8*)(Bc + base + 0) = c0;
    *(bf16x8*)(Bc + base + 8) = c1;
    #pragma unroll
    for (int c = 2; c < 16; ++c) *(bf16x8*)(Bc + base + c * 8) = z;
}

// ---------------------------------------------------------------------------
// Kernel 2: main pass, LDS-staged.
// Block = (split, rowtile): 16 rows x 4000 cols. Per tile (256 cols):
//   stage [16][256] f32 into LDS with fully-contiguous 1KB/row wave loads,
//   XOR-swizzled ((row&7)<<4) to kill the 1KB-row-stride bank conflict;
//   4 waves each take 2 of the 8 MFMA k-steps (k-partial accumulators);
//   epilogue cross-wave reduce in LDS, write P[row][split][18].
// ---------------------------------------------------------------------------
__global__ __launch_bounds__(256, 4) void fm_main(
        const float* __restrict__ x,
        const short* __restrict__ Bv, const short* __restrict__ Bc,
        float* __restrict__ P) {
    const int bid     = blockIdx.x;
    const int split   = bid / ROWTILES;   // split-major: all XCDs share one
    const int rowtile = bid % ROWTILES;   // split's 256KB B-slice in L2
    const int lane = threadIdx.x & 63;
    const int wave = threadIdx.x >> 6;
    const int c = lane & 15;              // MFMA A-row / B-col
    const int h = lane >> 4;              // k-group
    const int xc = (c & 7) << 4;          // read-side XOR swizzle

    __shared__ float lds[2][16 * 256];    // 2 x 16KB double buffer

    const int col0s = split * COLS_PER_SPLIT;
    f32x4 st[4];                          // staging regs: 4 rows x 16B

    f32x4 acc_s = {0.f, 0.f, 0.f, 0.f};
    f32x4 acc_l = {0.f, 0.f, 0.f, 0.f};
    f32x4 acc_q = {0.f, 0.f, 0.f, 0.f};

    auto issue = [&](int t) {
        const int ncols = (t < 15) ? 256 : 160;
        const bool ok = lane * 4 < ncols;
        const int colf = col0s + t * 256 + lane * 4;
        #pragma unroll
        for (int R = 0; R < 4; ++R) {
            int r = R * 4 + wave;
            const float* p = x + (size_t)(rowtile * 16 + r) * DIM + colf;
            if (ok) st[R] = __builtin_nontemporal_load((const f32x4*)p);
        }
    };
    auto writeLDS = [&](int buf, int t) {
        const int ncols = (t < 15) ? 256 : 160;
        const bool ok = lane * 4 < ncols;
        #pragma unroll
        for (int R = 0; R < 4; ++R) {
            int r = R * 4 + wave;
            int off = r * 256 + ((((lane * 16) ^ ((r & 7) << 4))) >> 2);
            if (ok) *(f32x4*)&lds[buf][off] = st[R];
        }
    };
    auto compute = [&](int buf, int t) {
        const int nsteps = (t < 15) ? 8 : 5;
        const int jbase = split * 125 + t * 8;
        #pragma unroll
        for (int ss = 0; ss < 2; ++ss) {
            int s = wave * 2 + ss;
            if (s < nsteps) {
                bf16x8 bv = *(const bf16x8*)(Bv + (size_t)(jbase + s) * 512 + h * 128 + c * 8);
                bf16x8 bc = *(const bf16x8*)(Bc + (size_t)(jbase + s) * 512 + h * 128 + c * 8);
                int W = s * 128 + h * 32;
                const float* base = &lds[buf][c * 256];
                f32x4 xa = *(const f32x4*)(base + ((W ^ xc) >> 2));
                f32x4 xb = *(const f32x4*)(base + (((W + 16) ^ xc) >> 2));
                bf16x8 a1, a2;
                #pragma unroll
                for (int i = 0; i < 4; ++i) {
                    a1[i]     = f2bf(xa[i]);
                    a1[i + 4] = f2bf(xb[i]);
                    a2[i]     = f2bf(xa[i] * xa[i]);
                    a2[i + 4] = f2bf(xb[i] * xb[i]);
                }
                acc_s = __builtin_amdgcn_mfma_f32_16x16x32_bf16(a1, bv, acc_s, 0, 0, 0);
                acc_l = __builtin_amdgcn_mfma_f32_16x16x32_bf16(a1, bc, acc_l, 0, 0, 0);
                acc_q = __builtin_amdgcn_mfma_f32_16x16x32_bf16(a2, bc, acc_q, 0, 0, 0);
            }
        }
    };

    // pipeline: one barrier per tile, disjoint double buffers
    issue(0);
    writeLDS(0, 0);                       // compiler inserts vmcnt wait
    for (int t = 0; t < NTILES; ++t) {
        if (t + 1 < NTILES) issue(t + 1);
        __syncthreads();                  // buf[t&1] writes visible
        compute(t & 1, t);
        if (t + 1 < NTILES) writeLDS((t + 1) & 1, t + 1);
    }

    // epilogue: cross-wave k-partial reduction
    __syncthreads();
    float* red = &lds[0][0];              // 4 waves x 64 lanes x 12 = 12KB
    int rbase = (wave * 64 + lane) * 12;
    #pragma unroll
    for (int i = 0; i < 4; ++i) {
        red[rbase + i]     = acc_s[i];
        red[rbase + 4 + i] = acc_l[i];
        red[rbase + 8 + i] = acc_q[i];
    }
    __syncthreads();
    if (wave == 0) {
        f32x4 s = {0,0,0,0}, l = {0,0,0,0}, q = {0,0,0,0};
        #pragma unroll
        for (int wv = 0; wv < 4; ++wv) {
            const float* rp = &red[(wv * 64 + lane) * 12];
            #pragma unroll
            for (int i = 0; i < 4; ++i) {
                s[i] += rp[i]; l[i] += rp[4 + i]; q[i] += rp[8 + i];
            }
        }
        // C/D layout: col = lane&15, row = (lane>>4)*4 + reg  [verified m89]
        #pragma unroll
        for (int r = 0; r < 4; ++r) {
            size_t row = (size_t)rowtile * 16 + h * 4 + r;
            float* Pp = P + (row * NSPLIT + split) * 18;
            Pp[c] = s[r];
            if (c == 0) Pp[16] = l[r];
            if (c == 1) Pp[17] = q[r];
        }
    }
}

// ---------------------------------------------------------------------------
// Kernel 3: reduce partials. One wave per batch row; lane = chunk (<25).
// out[b] = lin + 0.5*(sum_k s_k^2 - ss)
// ---------------------------------------------------------------------------
__global__ __launch_bounds__(64) void fm_reduce(const float* __restrict__ P,
                                                float* __restrict__ out) {
    int b = blockIdx.x;
    int lane = threadIdx.x;               // 0..63; chunks 0..24 active
    float r[18];
    if (lane < NSPLIT) {
        const float* q = P + ((size_t)b * NSPLIT + lane) * 18;
        #pragma unroll
        for (int i = 0; i < 18; ++i) r[i] = q[i];
    } else {
        #pragma unroll
        for (int i = 0; i < 18; ++i) r[i] = 0.f;
    }
    #pragma unroll
    for (int off = 32; off > 0; off >>= 1) {
        #pragma unroll
        for (int i = 0; i < 18; ++i) r[i] += __shfl_xor(r[i], off, 64);
    }
    if (lane == 0) {
        float acc = r[16] - 0.5f * r[17];
        #pragma unroll
        for (int k = 0; k < 16; ++k) acc += 0.5f * r[k] * r[k];
        out[b] = acc;
    }
}

// ---------------------------------------------------------------------------
extern "C" void kernel_launch(void* const* d_in, const int* in_sizes, int n_in,
                              void* d_out, int out_size, void* d_ws, size_t ws_size,
                              hipStream_t stream) {
    const float* x = (const float*)d_in[0];   // [2048, 100000]
    const float* w = (const float*)d_in[1];   // [100000, 1]
    const float* v = (const float*)d_in[2];   // [100000, 16]
    float* out = (float*)d_out;               // [2048]

    char* ws = (char*)d_ws;
    short* Bv = (short*)(ws);                 // 3.2 MB
    short* Bc = (short*)(ws + 3200000);       // 3.2 MB
    float* P  = (float*)(ws + 6400000);       // 2048*25*18*4 = 3.69 MB

    fm_pack<<<(STEPS * 4 + 255) / 256, 256, 0, stream>>>(w, v, Bv, Bc);
    fm_main<<<NSPLIT * ROWTILES, 256, 0, stream>>>(x, Bv, Bc, P);
    fm_reduce<<<BATCH, 64, 0, stream>>>(P, out);
}

// Round 4
// 186.096 us; speedup vs baseline: 1.3802x; 1.0260x over previous
//
#include <hip/hip_runtime.h>
#include <hip/hip_bf16.h>

#define BATCH 2048
#define DIM   100000
#define STEPS 3125              // DIM / 32 (exact)
#define NSPLIT 25               // column splits; 100000/25 = 4000 = 15*256 + 160
#define COLS_PER_SPLIT 4000
#define NTILES 16               // 15 full tiles of 256 + 1 tail tile of 160
#define ROWTILES 128            // 2048 / 16

typedef float f32x4  __attribute__((ext_vector_type(4)));
typedef short bf16x8 __attribute__((ext_vector_type(8)));

// f32 -> bf16 bits via HW convert (compiler pairs into v_cvt_pk_bf16_f32)
__device__ __forceinline__ short f2bf(float f) {
    return (short)__builtin_bit_cast(unsigned short, __float2bfloat16(f));
}

// ---------------------------------------------------------------------------
// Kernel 1: pack B operands into MFMA fragment order (bf16).
// Layout: B[j][h][c][i], j = d/32, h = (d/8)&3, i = d&7, c = column 0..15.
// One thread per (j,h): handles 8 consecutive d, 16B-vector stores.
// ---------------------------------------------------------------------------
__global__ __launch_bounds__(128) void fm_pack(
        const float* __restrict__ w, const float* __restrict__ v,
        short* __restrict__ Bv, short* __restrict__ Bc) {
    int t = blockIdx.x * blockDim.x + threadIdx.x;
    if (t >= STEPS * 4) return;
    int j = t >> 2, h = t & 3;
    int d0 = j * 32 + h * 8;
    size_t base = (size_t)j * 512 + (size_t)h * 128;

    short bv[16][8];
    float v2s[8];
    short wbits[8];
    #pragma unroll
    for (int i = 0; i < 8; ++i) {
        const f32x4* vp = (const f32x4*)(v + (size_t)(d0 + i) * 16);
        f32x4 r0 = vp[0], r1 = vp[1], r2 = vp[2], r3 = vp[3];
        float s = 0.f;
        #pragma unroll
        for (int q = 0; q < 4; ++q) {
            s += r0[q]*r0[q] + r1[q]*r1[q] + r2[q]*r2[q] + r3[q]*r3[q];
            bv[q + 0][i]  = f2bf(r0[q]);
            bv[q + 4][i]  = f2bf(r1[q]);
            bv[q + 8][i]  = f2bf(r2[q]);
            bv[q + 12][i] = f2bf(r3[q]);
        }
        v2s[i] = s;
        wbits[i] = f2bf(w[d0 + i]);
    }
    #pragma unroll
    for (int c = 0; c < 16; ++c) {
        bf16x8 o;
        #pragma unroll
        for (int i = 0; i < 8; ++i) o[i] = bv[c][i];
        *(bf16x8*)(Bv + base + c * 8) = o;
    }
    bf16x8 z = (bf16x8)0;
    bf16x8 c0, c1;
    #pragma unroll
    for (int i = 0; i < 8; ++i) { c0[i] = wbits[i]; c1[i] = f2bf(v2s[i]); }
    *(bf16x8*)(Bc + base + 0) = c0;
    *(bf16x8*)(Bc + base + 8) = c1;
    #pragma unroll
    for (int c = 2; c < 16; ++c) *(bf16x8*)(Bc + base + c * 8) = z;
}

// ---------------------------------------------------------------------------
// Kernel 2: main pass, LDS-staged, 2-tile-deep register prefetch.
// Per tile: barrier -> compute(t) -> issue(t+2) -> writeLDS(t+1).
// writeLDS(t+1) waits only its own 4 loads (counted vmcnt: t+2's stay in
// flight) -> outstanding x-loads never drain to zero.
// ---------------------------------------------------------------------------
__global__ __launch_bounds__(256, 4) void fm_main(
        const float* __restrict__ x,
        const short* __restrict__ Bv, const short* __restrict__ Bc,
        float* __restrict__ P) {
    const int bid     = blockIdx.x;
    const int split   = bid / ROWTILES;   // split-major: all XCDs share one
    const int rowtile = bid % ROWTILES;   // split's B-slice in L2
    const int lane = threadIdx.x & 63;
    const int wave = threadIdx.x >> 6;
    const int c = lane & 15;              // MFMA A-row / B-col
    const int h = lane >> 4;              // k-group
    const int xc = (c & 7) << 4;          // read-side XOR swizzle

    __shared__ float lds[2][16 * 256];    // 2 x 16KB double buffer

    const int col0s = split * COLS_PER_SPLIT;
    f32x4 stA[4], stB[4];                 // two named staging sets (static idx)

    f32x4 acc_s = {0.f, 0.f, 0.f, 0.f};
    f32x4 acc_l = {0.f, 0.f, 0.f, 0.f};
    f32x4 acc_q = {0.f, 0.f, 0.f, 0.f};

    auto issue = [&](f32x4 (&st)[4], int t) {
        if (t >= NTILES) return;
        const int ncols = (t < 15) ? 256 : 160;
        const bool ok = lane * 4 < ncols;
        const int colf = col0s + t * 256 + lane * 4;
        #pragma unroll
        for (int R = 0; R < 4; ++R) {
            int r = R * 4 + wave;
            const float* p = x + (size_t)(rowtile * 16 + r) * DIM + colf;
            if (ok) st[R] = __builtin_nontemporal_load((const f32x4*)p);
        }
    };
    auto writeLDS = [&](int buf, f32x4 (&st)[4], int t) {
        if (t >= NTILES) return;
        const int ncols = (t < 15) ? 256 : 160;
        const bool ok = lane * 4 < ncols;
        #pragma unroll
        for (int R = 0; R < 4; ++R) {
            int r = R * 4 + wave;
            int off = r * 256 + ((((lane * 16) ^ ((r & 7) << 4))) >> 2);
            if (ok) *(f32x4*)&lds[buf][off] = st[R];
        }
    };
    auto compute = [&](int buf, int t) {
        const int nsteps = (t < 15) ? 8 : 5;
        const int jbase = split * 125 + t * 8;
        #pragma unroll
        for (int ss = 0; ss < 2; ++ss) {
            int s = wave * 2 + ss;
            if (s < nsteps) {
                bf16x8 bv = *(const bf16x8*)(Bv + (size_t)(jbase + s) * 512 + h * 128 + c * 8);
                bf16x8 bc = *(const bf16x8*)(Bc + (size_t)(jbase + s) * 512 + h * 128 + c * 8);
                int W = s * 128 + h * 32;
                const float* base = &lds[buf][c * 256];
                f32x4 xa = *(const f32x4*)(base + ((W ^ xc) >> 2));
                f32x4 xb = *(const f32x4*)(base + (((W + 16) ^ xc) >> 2));
                bf16x8 a1, a2;
                #pragma unroll
                for (int i = 0; i < 4; ++i) {
                    a1[i]     = f2bf(xa[i]);
                    a1[i + 4] = f2bf(xb[i]);
                    a2[i]     = f2bf(xa[i] * xa[i]);
                    a2[i + 4] = f2bf(xb[i] * xb[i]);
                }
                acc_s = __builtin_amdgcn_mfma_f32_16x16x32_bf16(a1, bv, acc_s, 0, 0, 0);
                acc_l = __builtin_amdgcn_mfma_f32_16x16x32_bf16(a1, bc, acc_l, 0, 0, 0);
                acc_q = __builtin_amdgcn_mfma_f32_16x16x32_bf16(a2, bc, acc_q, 0, 0, 0);
            }
        }
    };

    // prologue: tiles 0,1 in flight; tile0 -> LDS buf0
    issue(stA, 0);
    issue(stB, 1);
    writeLDS(0, stA, 0);
    // steady state, hand-unrolled x2 for static stA/stB selection
    for (int tt = 0; tt < NTILES; tt += 2) {
        __syncthreads();
        compute(0, tt);
        issue(stA, tt + 2);
        writeLDS(1, stB, tt + 1);
        __syncthreads();
        compute(1, tt + 1);
        issue(stB, tt + 3);
        writeLDS(0, stA, tt + 2);
    }

    // epilogue: cross-wave k-partial reduction
    __syncthreads();
    float* red = &lds[0][0];              // 4 waves x 64 lanes x 12 floats
    int rbase = (wave * 64 + lane) * 12;
    #pragma unroll
    for (int i = 0; i < 4; ++i) {
        red[rbase + i]     = acc_s[i];
        red[rbase + 4 + i] = acc_l[i];
        red[rbase + 8 + i] = acc_q[i];
    }
    __syncthreads();
    if (wave == 0) {
        f32x4 s = {0,0,0,0}, l = {0,0,0,0}, q = {0,0,0,0};
        #pragma unroll
        for (int wv = 0; wv < 4; ++wv) {
            const float* rp = &red[(wv * 64 + lane) * 12];
            #pragma unroll
            for (int i = 0; i < 4; ++i) {
                s[i] += rp[i]; l[i] += rp[4 + i]; q[i] += rp[8 + i];
            }
        }
        // C/D layout: col = lane&15, row = (lane>>4)*4 + reg  [verified m89]
        #pragma unroll
        for (int r = 0; r < 4; ++r) {
            size_t row = (size_t)rowtile * 16 + h * 4 + r;
            float* Pp = P + (row * NSPLIT + split) * 18;
            Pp[c] = s[r];
            if (c == 0) Pp[16] = l[r];
            if (c == 1) Pp[17] = q[r];
        }
    }
}

// ---------------------------------------------------------------------------
// Kernel 3: reduce partials. One wave per batch row; lane = chunk (<25).
// out[b] = lin + 0.5*(sum_k s_k^2 - ss)
// ---------------------------------------------------------------------------
__global__ __launch_bounds__(64) void fm_reduce(const float* __restrict__ P,
                                                float* __restrict__ out) {
    int b = blockIdx.x;
    int lane = threadIdx.x;               // 0..63; chunks 0..24 active
    float r[18];
    if (lane < NSPLIT) {
        const float* q = P + ((size_t)b * NSPLIT + lane) * 18;
        #pragma unroll
        for (int i = 0; i < 18; ++i) r[i] = q[i];
    } else {
        #pragma unroll
        for (int i = 0; i < 18; ++i) r[i] = 0.f;
    }
    #pragma unroll
    for (int off = 32; off > 0; off >>= 1) {
        #pragma unroll
        for (int i = 0; i < 18; ++i) r[i] += __shfl_xor(r[i], off, 64);
    }
    if (lane == 0) {
        float acc = r[16] - 0.5f * r[17];
        #pragma unroll
        for (int k = 0; k < 16; ++k) acc += 0.5f * r[k] * r[k];
        out[b] = acc;
    }
}

// ---------------------------------------------------------------------------
extern "C" void kernel_launch(void* const* d_in, const int* in_sizes, int n_in,
                              void* d_out, int out_size, void* d_ws, size_t ws_size,
                              hipStream_t stream) {
    const float* x = (const float*)d_in[0];   // [2048, 100000]
    const float* w = (const float*)d_in[1];   // [100000, 1]
    const float* v = (const float*)d_in[2];   // [100000, 16]
    float* out = (float*)d_out;               // [2048]

    char* ws = (char*)d_ws;
    short* Bv = (short*)(ws);                 // 3.2 MB
    short* Bc = (short*)(ws + 3200000);       // 3.2 MB
    float* P  = (float*)(ws + 6400000);       // 2048*25*18*4 = 3.69 MB

    fm_pack<<<(STEPS * 4 + 127) / 128, 128, 0, stream>>>(w, v, Bv, Bc);
    fm_main<<<NSPLIT * ROWTILES, 256, 0, stream>>>(x, Bv, Bc, P);
    fm_reduce<<<BATCH, 64, 0, stream>>>(P, out);
}

// Round 5
// 178.167 us; speedup vs baseline: 1.4416x; 1.0445x over previous
//
#include <hip/hip_runtime.h>
#include <hip/hip_bf16.h>

#define BATCH 2048
#define DIM   100000
#define STEPS 3125              // DIM / 32 (exact)
#define NSPLIT 8                // 5 splits of 391 steps + 3 of 390 (=3125)
#define NTILES 49               // 48 full 8-step tiles + 1 tail (6 or 7 steps)
#define ROWTILES 128            // 2048 / 16

typedef float f32x4  __attribute__((ext_vector_type(4)));
typedef short bf16x8 __attribute__((ext_vector_type(8)));

// f32 -> bf16 bits via HW convert (compiler pairs into v_cvt_pk_bf16_f32)
__device__ __forceinline__ short f2bf(float f) {
    return (short)__builtin_bit_cast(unsigned short, __float2bfloat16(f));
}

// ---------------------------------------------------------------------------
// Kernel 1: pack B operands into MFMA fragment order (bf16).
// Layout: B[j][h][c][i], j = d/32, h = (d/8)&3, i = d&7, c = column 0..15.
// ---------------------------------------------------------------------------
__global__ __launch_bounds__(128) void fm_pack(
        const float* __restrict__ w, const float* __restrict__ v,
        short* __restrict__ Bv, short* __restrict__ Bc) {
    int t = blockIdx.x * blockDim.x + threadIdx.x;
    if (t >= STEPS * 4) return;
    int j = t >> 2, h = t & 3;
    int d0 = j * 32 + h * 8;
    size_t base = (size_t)j * 512 + (size_t)h * 128;

    short bv[16][8];
    float v2s[8];
    short wbits[8];
    #pragma unroll
    for (int i = 0; i < 8; ++i) {
        const f32x4* vp = (const f32x4*)(v + (size_t)(d0 + i) * 16);
        f32x4 r0 = vp[0], r1 = vp[1], r2 = vp[2], r3 = vp[3];
        float s = 0.f;
        #pragma unroll
        for (int q = 0; q < 4; ++q) {
            s += r0[q]*r0[q] + r1[q]*r1[q] + r2[q]*r2[q] + r3[q]*r3[q];
            bv[q + 0][i]  = f2bf(r0[q]);
            bv[q + 4][i]  = f2bf(r1[q]);
            bv[q + 8][i]  = f2bf(r2[q]);
            bv[q + 12][i] = f2bf(r3[q]);
        }
        v2s[i] = s;
        wbits[i] = f2bf(w[d0 + i]);
    }
    #pragma unroll
    for (int c = 0; c < 16; ++c) {
        bf16x8 o;
        #pragma unroll
        for (int i = 0; i < 8; ++i) o[i] = bv[c][i];
        *(bf16x8*)(Bv + base + c * 8) = o;
    }
    bf16x8 z = (bf16x8)0;
    bf16x8 c0, c1;
    #pragma unroll
    for (int i = 0; i < 8; ++i) { c0[i] = wbits[i]; c1[i] = f2bf(v2s[i]); }
    *(bf16x8*)(Bc + base + 0) = c0;
    *(bf16x8*)(Bc + base + 8) = c1;
    #pragma unroll
    for (int c = 2; c < 16; ++c) *(bf16x8*)(Bc + base + c * 8) = z;
}

// ---------------------------------------------------------------------------
// Kernel 2: main pass. Grid = exactly 1024 uniform blocks (one generation,
// no tail). split = bid&7 -> all of a split's blocks land on one XCD
// (round-robin dispatch), so its ~800KB B-slice stays in that XCD's L2.
// Splits: 5x391 steps + 3x390 steps (32-col granules, no padding).
// Per tile: barrier -> compute(t) -> issue(t+2) -> writeLDS(t+1).
// ---------------------------------------------------------------------------
__global__ __launch_bounds__(256, 4) void fm_main(
        const float* __restrict__ x,
        const short* __restrict__ Bv, const short* __restrict__ Bc,
        float* __restrict__ P) {
    const int bid     = blockIdx.x;
    const int split   = bid & 7;
    const int rowtile = bid >> 3;
    const int lane = threadIdx.x & 63;
    const int wave = threadIdx.x >> 6;
    const int c = lane & 15;              // MFMA A-row / B-col
    const int h = lane >> 4;              // k-group
    const int xc = (c & 7) << 4;          // read-side XOR swizzle

    const int step_base  = split * 390 + (split < 5 ? split : 5);
    const int tail_steps = 6 + (split < 5 ? 1 : 0);   // steps in tile 48

    __shared__ float lds[2][16 * 256];    // 2 x 16KB double buffer

    const int col0s = step_base * 32;
    f32x4 stA[4], stB[4];                 // two named staging sets (static idx)

    f32x4 acc_s = {0.f, 0.f, 0.f, 0.f};
    f32x4 acc_l = {0.f, 0.f, 0.f, 0.f};
    f32x4 acc_q = {0.f, 0.f, 0.f, 0.f};

    auto issue = [&](f32x4 (&st)[4], int t) {
        if (t >= NTILES) return;
        const int ncols = (t < 48) ? 256 : tail_steps * 32;
        const bool ok = lane * 4 < ncols;
        const int colf = col0s + t * 256 + lane * 4;
        #pragma unroll
        for (int R = 0; R < 4; ++R) {
            int r = R * 4 + wave;
            const float* p = x + (size_t)(rowtile * 16 + r) * DIM + colf;
            if (ok) st[R] = *(const f32x4*)p;
        }
    };
    auto writeLDS = [&](int buf, f32x4 (&st)[4], int t) {
        if (t >= NTILES) return;
        const int ncols = (t < 48) ? 256 : tail_steps * 32;
        const bool ok = lane * 4 < ncols;
        #pragma unroll
        for (int R = 0; R < 4; ++R) {
            int r = R * 4 + wave;
            int off = r * 256 + ((((lane * 16) ^ ((r & 7) << 4))) >> 2);
            if (ok) *(f32x4*)&lds[buf][off] = st[R];
        }
    };
    auto compute = [&](int buf, int t) {
        if (t >= NTILES) return;
        const int nsteps = (t < 48) ? 8 : tail_steps;
        const int jbase = step_base + t * 8;
        #pragma unroll
        for (int ss = 0; ss < 2; ++ss) {
            int s = wave * 2 + ss;
            if (s < nsteps) {
                bf16x8 bv = *(const bf16x8*)(Bv + (size_t)(jbase + s) * 512 + h * 128 + c * 8);
                bf16x8 bc = *(const bf16x8*)(Bc + (size_t)(jbase + s) * 512 + h * 128 + c * 8);
                int W = s * 128 + h * 32;
                const float* base = &lds[buf][c * 256];
                f32x4 xa = *(const f32x4*)(base + ((W ^ xc) >> 2));
                f32x4 xb = *(const f32x4*)(base + (((W + 16) ^ xc) >> 2));
                bf16x8 a1, a2;
                #pragma unroll
                for (int i = 0; i < 4; ++i) {
                    a1[i]     = f2bf(xa[i]);
                    a1[i + 4] = f2bf(xb[i]);
                    a2[i]     = f2bf(xa[i] * xa[i]);
                    a2[i + 4] = f2bf(xb[i] * xb[i]);
                }
                acc_s = __builtin_amdgcn_mfma_f32_16x16x32_bf16(a1, bv, acc_s, 0, 0, 0);
                acc_l = __builtin_amdgcn_mfma_f32_16x16x32_bf16(a1, bc, acc_l, 0, 0, 0);
                acc_q = __builtin_amdgcn_mfma_f32_16x16x32_bf16(a2, bc, acc_q, 0, 0, 0);
            }
        }
    };

    // prologue: tiles 0,1 in flight; tile0 -> LDS buf0
    issue(stA, 0);
    issue(stB, 1);
    writeLDS(0, stA, 0);
    // steady state, hand-unrolled x2 for static stA/stB selection (49 tiles)
    for (int tt = 0; tt < NTILES; tt += 2) {
        __syncthreads();
        compute(0, tt);
        issue(stA, tt + 2);
        writeLDS(1, stB, tt + 1);
        __syncthreads();
        compute(1, tt + 1);
        issue(stB, tt + 3);
        writeLDS(0, stA, tt + 2);
    }

    // epilogue: cross-wave k-partial reduction
    __syncthreads();
    float* red = &lds[0][0];              // 4 waves x 64 lanes x 12 floats
    int rbase = (wave * 64 + lane) * 12;
    #pragma unroll
    for (int i = 0; i < 4; ++i) {
        red[rbase + i]     = acc_s[i];
        red[rbase + 4 + i] = acc_l[i];
        red[rbase + 8 + i] = acc_q[i];
    }
    __syncthreads();
    if (wave == 0) {
        f32x4 s = {0,0,0,0}, l = {0,0,0,0}, q = {0,0,0,0};
        #pragma unroll
        for (int wv = 0; wv < 4; ++wv) {
            const float* rp = &red[(wv * 64 + lane) * 12];
            #pragma unroll
            for (int i = 0; i < 4; ++i) {
                s[i] += rp[i]; l[i] += rp[4 + i]; q[i] += rp[8 + i];
            }
        }
        // C/D layout: col = lane&15, row = (lane>>4)*4 + reg  [verified m89]
        #pragma unroll
        for (int r = 0; r < 4; ++r) {
            size_t row = (size_t)rowtile * 16 + h * 4 + r;
            float* Pp = P + (row * NSPLIT + split) * 18;
            Pp[c] = s[r];
            if (c == 0) Pp[16] = l[r];
            if (c == 1) Pp[17] = q[r];
        }
    }
}

// ---------------------------------------------------------------------------
// Kernel 3: reduce partials. One wave per batch row; lane = split (<8).
// out[b] = lin + 0.5*(sum_k s_k^2 - ss)
// ---------------------------------------------------------------------------
__global__ __launch_bounds__(64) void fm_reduce(const float* __restrict__ P,
                                                float* __restrict__ out) {
    int b = blockIdx.x;
    int lane = threadIdx.x;               // 0..63; splits 0..7 active
    float r[18];
    if (lane < NSPLIT) {
        const float* q = P + ((size_t)b * NSPLIT + lane) * 18;
        #pragma unroll
        for (int i = 0; i < 18; ++i) r[i] = q[i];
    } else {
        #pragma unroll
        for (int i = 0; i < 18; ++i) r[i] = 0.f;
    }
    #pragma unroll
    for (int off = 4; off > 0; off >>= 1) {
        #pragma unroll
        for (int i = 0; i < 18; ++i) r[i] += __shfl_xor(r[i], off, 64);
    }
    if (lane == 0) {
        float acc = r[16] - 0.5f * r[17];
        #pragma unroll
        for (int k = 0; k < 16; ++k) acc += 0.5f * r[k] * r[k];
        out[b] = acc;
    }
}

// ---------------------------------------------------------------------------
extern "C" void kernel_launch(void* const* d_in, const int* in_sizes, int n_in,
                              void* d_out, int out_size, void* d_ws, size_t ws_size,
                              hipStream_t stream) {
    const float* x = (const float*)d_in[0];   // [2048, 100000]
    const float* w = (const float*)d_in[1];   // [100000, 1]
    const float* v = (const float*)d_in[2];   // [100000, 16]
    float* out = (float*)d_out;               // [2048]

    char* ws = (char*)d_ws;
    short* Bv = (short*)(ws);                 // 3.2 MB
    short* Bc = (short*)(ws + 3200000);       // 3.2 MB
    float* P  = (float*)(ws + 6400000);       // 2048*8*18*4 = 1.18 MB

    fm_pack<<<(STEPS * 4 + 127) / 128, 128, 0, stream>>>(w, v, Bv, Bc);
    fm_main<<<NSPLIT * ROWTILES, 256, 0, stream>>>(x, Bv, Bc, P);
    fm_reduce<<<BATCH, 64, 0, stream>>>(P, out);
}

// Round 6
// 160.190 us; speedup vs baseline: 1.6034x; 1.1122x over previous
//
#include <hip/hip_runtime.h>
#include <hip/hip_bf16.h>

#define BATCH 2048
#define DIM   100000
#define STEPS 3125              // DIM / 32 (exact)
#define NSPLIT 8                // 5 splits of 391 steps + 3 of 390 (=3125)
#define NTILES 49               // 48 full 8-step tiles + 1 tail (6 or 7 steps)
#define ROWTILES 128            // 2048 / 16

typedef float f32x4  __attribute__((ext_vector_type(4)));
typedef short bf16x8 __attribute__((ext_vector_type(8)));

// f32 -> bf16 bits via HW convert (compiler pairs into v_cvt_pk_bf16_f32)
__device__ __forceinline__ short f2bf(float f) {
    return (short)__builtin_bit_cast(unsigned short, __float2bfloat16(f));
}

// ---------------------------------------------------------------------------
// Kernel 1: pack B operands into MFMA fragment order (bf16).  (unchanged R5)
// Layout: B[j][h][c][i], j = d/32, h = (d/8)&3, i = d&7, c = column 0..15.
// ---------------------------------------------------------------------------
__global__ __launch_bounds__(128) void fm_pack(
        const float* __restrict__ w, const float* __restrict__ v,
        short* __restrict__ Bv, short* __restrict__ Bc) {
    int t = blockIdx.x * blockDim.x + threadIdx.x;
    if (t >= STEPS * 4) return;
    int j = t >> 2, h = t & 3;
    int d0 = j * 32 + h * 8;
    size_t base = (size_t)j * 512 + (size_t)h * 128;

    short bv[16][8];
    float v2s[8];
    short wbits[8];
    #pragma unroll
    for (int i = 0; i < 8; ++i) {
        const f32x4* vp = (const f32x4*)(v + (size_t)(d0 + i) * 16);
        f32x4 r0 = vp[0], r1 = vp[1], r2 = vp[2], r3 = vp[3];
        float s = 0.f;
        #pragma unroll
        for (int q = 0; q < 4; ++q) {
            s += r0[q]*r0[q] + r1[q]*r1[q] + r2[q]*r2[q] + r3[q]*r3[q];
            bv[q + 0][i]  = f2bf(r0[q]);
            bv[q + 4][i]  = f2bf(r1[q]);
            bv[q + 8][i]  = f2bf(r2[q]);
            bv[q + 12][i] = f2bf(r3[q]);
        }
        v2s[i] = s;
        wbits[i] = f2bf(w[d0 + i]);
    }
    #pragma unroll
    for (int c = 0; c < 16; ++c) {
        bf16x8 o;
        #pragma unroll
        for (int i = 0; i < 8; ++i) o[i] = bv[c][i];
        *(bf16x8*)(Bv + base + c * 8) = o;
    }
    bf16x8 z = (bf16x8)0;
    bf16x8 c0, c1;
    #pragma unroll
    for (int i = 0; i < 8; ++i) { c0[i] = wbits[i]; c1[i] = f2bf(v2s[i]); }
    *(bf16x8*)(Bc + base + 0) = c0;
    *(bf16x8*)(Bc + base + 8) = c1;
    #pragma unroll
    for (int c = 2; c < 16; ++c) *(bf16x8*)(Bc + base + c * 8) = z;
}

// ---------------------------------------------------------------------------
// Kernel 2: main pass. 1024 uniform blocks (one generation, no tail).
// split = bid&7 pins each split's B-slice to one XCD's L2.
// New this round: (1) nontemporal x loads (no L2/L3 allocate for the
// single-use 800MB stream); (2) B-fragments register-prefetched one tile
// ahead (two named sets, static indexing) so compute never waits on L2.
// ---------------------------------------------------------------------------
__global__ __launch_bounds__(256, 4) void fm_main(
        const float* __restrict__ x,
        const short* __restrict__ Bv, const short* __restrict__ Bc,
        float* __restrict__ P) {
    const int bid     = blockIdx.x;
    const int split   = bid & 7;
    const int rowtile = bid >> 3;
    const int lane = threadIdx.x & 63;
    const int wave = threadIdx.x >> 6;
    const int c = lane & 15;              // MFMA A-row / B-col
    const int h = lane >> 4;              // k-group
    const int xc = (c & 7) << 4;          // read-side XOR swizzle

    const int step_base  = split * 390 + (split < 5 ? split : 5);
    const int tail_steps = 6 + (split < 5 ? 1 : 0);   // steps in tile 48

    __shared__ float lds[2][16 * 256];    // 2 x 16KB double buffer

    const int col0s = step_base * 32;
    f32x4 stA[4], stB[4];                 // x staging sets (static idx)
    bf16x8 pv0, pc0, pv1, pc1;            // B set 0 (this wave's 2 steps)
    bf16x8 qv0, qc0, qv1, qc1;            // B set 1

    f32x4 acc_s = {0.f, 0.f, 0.f, 0.f};
    f32x4 acc_l = {0.f, 0.f, 0.f, 0.f};
    f32x4 acc_q = {0.f, 0.f, 0.f, 0.f};

    auto issue = [&](f32x4 (&st)[4], int t) {
        if (t >= NTILES) return;
        const int ncols = (t < 48) ? 256 : tail_steps * 32;
        const bool ok = lane * 4 < ncols;
        const int colf = col0s + t * 256 + lane * 4;
        #pragma unroll
        for (int R = 0; R < 4; ++R) {
            int r = R * 4 + wave;
            const float* p = x + (size_t)(rowtile * 16 + r) * DIM + colf;
            if (ok) st[R] = __builtin_nontemporal_load((const f32x4*)p);
        }
    };
    auto writeLDS = [&](int buf, f32x4 (&st)[4], int t) {
        if (t >= NTILES) return;
        const int ncols = (t < 48) ? 256 : tail_steps * 32;
        const bool ok = lane * 4 < ncols;
        #pragma unroll
        for (int R = 0; R < 4; ++R) {
            int r = R * 4 + wave;
            int off = r * 256 + ((((lane * 16) ^ ((r & 7) << 4))) >> 2);
            if (ok) *(f32x4*)&lds[buf][off] = st[R];
        }
    };
    // prefetch B fragments for tile t into a named set (clamped: tail
    // overreads stay inside ws and are never consumed)
    auto loadB = [&](bf16x8& v0, bf16x8& c0, bf16x8& v1, bf16x8& c1, int t) {
        if (t >= NTILES) return;
        int jb = step_base + t * 8;
        int sa = jb + wave * 2;     if (sa > STEPS - 1) sa = STEPS - 1;
        int sb = jb + wave * 2 + 1; if (sb > STEPS - 1) sb = STEPS - 1;
        size_t oa = (size_t)sa * 512 + h * 128 + c * 8;
        size_t ob = (size_t)sb * 512 + h * 128 + c * 8;
        v0 = *(const bf16x8*)(Bv + oa);
        c0 = *(const bf16x8*)(Bc + oa);
        v1 = *(const bf16x8*)(Bv + ob);
        c1 = *(const bf16x8*)(Bc + ob);
    };
    auto compute = [&](int buf, int t, bf16x8 bv0, bf16x8 bc0,
                                       bf16x8 bv1, bf16x8 bc1) {
        if (t >= NTILES) return;
        const int nsteps = (t < 48) ? 8 : tail_steps;
        #pragma unroll
        for (int ss = 0; ss < 2; ++ss) {
            int s = wave * 2 + ss;
            if (s < nsteps) {
                bf16x8 bv = ss ? bv1 : bv0;
                bf16x8 bc = ss ? bc1 : bc0;
                int W = s * 128 + h * 32;
                const float* base = &lds[buf][c * 256];
                f32x4 xa = *(const f32x4*)(base + ((W ^ xc) >> 2));
                f32x4 xb = *(const f32x4*)(base + (((W + 16) ^ xc) >> 2));
                bf16x8 a1, a2;
                #pragma unroll
                for (int i = 0; i < 4; ++i) {
                    a1[i]     = f2bf(xa[i]);
                    a1[i + 4] = f2bf(xb[i]);
                    a2[i]     = f2bf(xa[i] * xa[i]);
                    a2[i + 4] = f2bf(xb[i] * xb[i]);
                }
                acc_s = __builtin_amdgcn_mfma_f32_16x16x32_bf16(a1, bv, acc_s, 0, 0, 0);
                acc_l = __builtin_amdgcn_mfma_f32_16x16x32_bf16(a1, bc, acc_l, 0, 0, 0);
                acc_q = __builtin_amdgcn_mfma_f32_16x16x32_bf16(a2, bc, acc_q, 0, 0, 0);
            }
        }
    };

    // prologue: x tiles 0,1 in flight; tile0 -> LDS buf0; B(0) -> set p
    issue(stA, 0);
    issue(stB, 1);
    loadB(pv0, pc0, pv1, pc1, 0);
    writeLDS(0, stA, 0);
    // steady state, hand-unrolled x2 (49 tiles; guards handle the odd tail)
    for (int tt = 0; tt < NTILES; tt += 2) {
        __syncthreads();
        loadB(qv0, qc0, qv1, qc1, tt + 1);   // B for next tile: issue early
        compute(0, tt, pv0, pc0, pv1, pc1);  // consumes B loaded a tile ago
        issue(stA, tt + 2);
        writeLDS(1, stB, tt + 1);
        __syncthreads();
        loadB(pv0, pc0, pv1, pc1, tt + 2);
        compute(1, tt + 1, qv0, qc0, qv1, qc1);
        issue(stB, tt + 3);
        writeLDS(0, stA, tt + 2);
    }

    // epilogue: cross-wave k-partial reduction
    __syncthreads();
    float* red = &lds[0][0];              // 4 waves x 64 lanes x 12 floats
    int rbase = (wave * 64 + lane) * 12;
    #pragma unroll
    for (int i = 0; i < 4; ++i) {
        red[rbase + i]     = acc_s[i];
        red[rbase + 4 + i] = acc_l[i];
        red[rbase + 8 + i] = acc_q[i];
    }
    __syncthreads();
    if (wave == 0) {
        f32x4 s = {0,0,0,0}, l = {0,0,0,0}, q = {0,0,0,0};
        #pragma unroll
        for (int wv = 0; wv < 4; ++wv) {
            const float* rp = &red[(wv * 64 + lane) * 12];
            #pragma unroll
            for (int i = 0; i < 4; ++i) {
                s[i] += rp[i]; l[i] += rp[4 + i]; q[i] += rp[8 + i];
            }
        }
        // C/D layout: col = lane&15, row = (lane>>4)*4 + reg  [verified m89]
        #pragma unroll
        for (int r = 0; r < 4; ++r) {
            size_t row = (size_t)rowtile * 16 + h * 4 + r;
            float* Pp = P + (row * NSPLIT + split) * 18;
            Pp[c] = s[r];
            if (c == 0) Pp[16] = l[r];
            if (c == 1) Pp[17] = q[r];
        }
    }
}

// ---------------------------------------------------------------------------
// Kernel 3: reduce partials. One wave per batch row; lane = split (<8).
// out[b] = lin + 0.5*(sum_k s_k^2 - ss)                       (unchanged R5)
// ---------------------------------------------------------------------------
__global__ __launch_bounds__(64) void fm_reduce(const float* __restrict__ P,
                                                float* __restrict__ out) {
    int b = blockIdx.x;
    int lane = threadIdx.x;               // 0..63; splits 0..7 active
    float r[18];
    if (lane < NSPLIT) {
        const float* q = P + ((size_t)b * NSPLIT + lane) * 18;
        #pragma unroll
        for (int i = 0; i < 18; ++i) r[i] = q[i];
    } else {
        #pragma unroll
        for (int i = 0; i < 18; ++i) r[i] = 0.f;
    }
    #pragma unroll
    for (int off = 4; off > 0; off >>= 1) {
        #pragma unroll
        for (int i = 0; i < 18; ++i) r[i] += __shfl_xor(r[i], off, 64);
    }
    if (lane == 0) {
        float acc = r[16] - 0.5f * r[17];
        #pragma unroll
        for (int k = 0; k < 16; ++k) acc += 0.5f * r[k] * r[k];
        out[b] = acc;
    }
}

// ---------------------------------------------------------------------------
extern "C" void kernel_launch(void* const* d_in, const int* in_sizes, int n_in,
                              void* d_out, int out_size, void* d_ws, size_t ws_size,
                              hipStream_t stream) {
    const float* x = (const float*)d_in[0];   // [2048, 100000]
    const float* w = (const float*)d_in[1];   // [100000, 1]
    const float* v = (const float*)d_in[2];   // [100000, 16]
    float* out = (float*)d_out;               // [2048]

    char* ws = (char*)d_ws;
    short* Bv = (short*)(ws);                 // 3.2 MB
    short* Bc = (short*)(ws + 3200000);       // 3.2 MB
    float* P  = (float*)(ws + 6400000);       // 2048*8*18*4 = 1.18 MB

    fm_pack<<<(STEPS * 4 + 127) / 128, 128, 0, stream>>>(w, v, Bv, Bc);
    fm_main<<<NSPLIT * ROWTILES, 256, 0, stream>>>(x, Bv, Bc, P);
    fm_reduce<<<BATCH, 64, 0, stream>>>(P, out);
}

// Round 7
// 158.457 us; speedup vs baseline: 1.6209x; 1.0109x over previous
//
#include <hip/hip_runtime.h>
#include <hip/hip_bf16.h>

#define BATCH 2048
#define DIM   100000
#define STEPS 3125              // DIM / 32 (exact)
#define NSPLIT 8                // 5 splits of 391 steps + 3 of 390 (=3125)
#define NTILES 25               // 24 full 16-step tiles + tail (7 or 6 steps)
#define ROWTILES 128            // 2048 / 16

typedef float f32x4  __attribute__((ext_vector_type(4)));
typedef short bf16x8 __attribute__((ext_vector_type(8)));
typedef short bf16x4 __attribute__((ext_vector_type(4)));

// f32 -> bf16 bits via HW convert (compiler pairs into v_cvt_pk_bf16_f32)
__device__ __forceinline__ short f2bf(float f) {
    return (short)__builtin_bit_cast(unsigned short, __float2bfloat16(f));
}
__device__ __forceinline__ float bf2f(short s) {
    unsigned u = ((unsigned)(unsigned short)s) << 16;
    return __builtin_bit_cast(float, u);
}

// ---------------------------------------------------------------------------
// Kernel 1: pack B operands, LDS-staged for full coalescing.
// Block = 256 thr handles 4 j-groups (128 d). Loads v/w contiguously,
// transposes via LDS, one 16B output vector per thread.
// Layout: B[j][h][c][i], j = d/32, h = (d/8)&3, i = d&7, c = column 0..15.
// ---------------------------------------------------------------------------
__global__ __launch_bounds__(256) void fm_pack(
        const float* __restrict__ w, const float* __restrict__ v,
        short* __restrict__ Bv, short* __restrict__ Bc) {
    __shared__ float vt[128][17];         // +1 pad: bank-spread columns
    __shared__ float wt[128];
    const int t  = threadIdx.x;
    const int jb = blockIdx.x * 4;
    const int d_base = jb * 32;
    const int nd = (DIM - d_base < 128) ? (DIM - d_base) : 128;

    // coalesced v load: 2048 f32 per block, 8 per thread
    #pragma unroll
    for (int q = 0; q < 2; ++q) {
        int e = t * 8 + q * 4;
        if (e < nd * 16) {
            f32x4 r = *(const f32x4*)(v + (size_t)d_base * 16 + e);
            #pragma unroll
            for (int i = 0; i < 4; ++i) vt[(e + i) >> 4][(e + i) & 15] = r[i];
        }
    }
    if (t < 32) {
        int d = t * 4;
        if (d < nd) {
            f32x4 r = *(const f32x4*)(w + d_base + d);
            #pragma unroll
            for (int i = 0; i < 4; ++i) if (d + i < nd) wt[d + i] = r[i];
        }
    }
    __syncthreads();

    const int jp = t >> 6;                // 0..3
    const int j  = jb + jp;
    if (j >= STEPS) return;
    const int rem = t & 63;
    const int h = rem >> 4, c = rem & 15;
    const int dl0 = jp * 32 + h * 8;
    size_t off = (size_t)j * 512 + h * 128 + c * 8;

    bf16x8 ov, oc;
    #pragma unroll
    for (int i = 0; i < 8; ++i) ov[i] = f2bf(vt[dl0 + i][c]);
    *(bf16x8*)(Bv + off) = ov;

    if (c == 0) {
        #pragma unroll
        for (int i = 0; i < 8; ++i) oc[i] = f2bf(wt[dl0 + i]);
    } else if (c == 1) {
        #pragma unroll
        for (int i = 0; i < 8; ++i) {
            float s = 0.f;
            #pragma unroll
            for (int k = 0; k < 16; ++k) { float vv = vt[dl0 + i][k]; s += vv * vv; }
            oc[i] = f2bf(s);
        }
    } else {
        oc = (bf16x8)0;
    }
    *(bf16x8*)(Bc + off) = oc;
}

// ---------------------------------------------------------------------------
// Kernel 2: main pass. 1024 uniform blocks (one generation). split = bid&7
// pins each split's B-slice to one XCD's L2. NEW: x staged in LDS as bf16,
// tile 16 rows x 512 cols (2KB burst per row per tile, 25 barriers not 49),
// a1 fragment read directly via one ds_read_b128.
// ---------------------------------------------------------------------------
__global__ __launch_bounds__(256, 4) void fm_main(
        const float* __restrict__ x,
        const short* __restrict__ Bv, const short* __restrict__ Bc,
        float* __restrict__ P) {
    const int bid     = blockIdx.x;
    const int split   = bid & 7;
    const int rowtile = bid >> 3;
    const int lane = threadIdx.x & 63;
    const int wave = threadIdx.x >> 6;
    const int c = lane & 15;              // MFMA A-row / B-col
    const int h = lane >> 4;              // k-group

    const int step_base  = split * 390 + (split < 5 ? split : 5);
    const int tail_steps = 6 + (split < 5 ? 1 : 0);   // steps in tile 24

    __shared__ short lds[2][16 * 512];    // bf16 tile: 2 x 16KB

    const int col0s = step_base * 32;
    f32x4 st[4][2];                       // x staging: 4 rows x 8 f32
    bf16x8 bvr[4], bcr[4];                // B frags, 4 steps/wave (unroll-idx)

    f32x4 acc_s = {0.f, 0.f, 0.f, 0.f};
    f32x4 acc_l = {0.f, 0.f, 0.f, 0.f};
    f32x4 acc_q = {0.f, 0.f, 0.f, 0.f};

    auto issue = [&](int t) {             // 2 contiguous 1KB wave-segments/row
        if (t >= NTILES) return;
        const int ncols = (t < 24) ? 512 : tail_steps * 32;
        const int colf = col0s + t * 512;
        #pragma unroll
        for (int R = 0; R < 4; ++R) {
            int r = wave * 4 + R;
            const float* p = x + (size_t)(rowtile * 16 + r) * DIM + colf;
            if (lane * 4 < ncols)
                st[R][0] = __builtin_nontemporal_load((const f32x4*)(p + lane * 4));
            if (256 + lane * 4 < ncols)
                st[R][1] = __builtin_nontemporal_load((const f32x4*)(p + 256 + lane * 4));
        }
    };
    auto writeLDS = [&](int buf, int t) { // convert f32->bf16, swizzled b64 x2
        if (t >= NTILES) return;
        const int ncols = (t < 24) ? 512 : tail_steps * 32;
        #pragma unroll
        for (int R = 0; R < 4; ++R) {
            int r = wave * 4 + R;
            int swz = (r & 7) << 4;
            char* base = (char*)&lds[buf][0];
            if (lane * 4 < ncols) {
                bf16x4 o; 
                #pragma unroll
                for (int i = 0; i < 4; ++i) o[i] = f2bf(st[R][0][i]);
                *(bf16x4*)(base + (r * 1024 + ((lane * 8) ^ swz))) = o;
            }
            if (256 + lane * 4 < ncols) {
                bf16x4 o;
                #pragma unroll
                for (int i = 0; i < 4; ++i) o[i] = f2bf(st[R][1][i]);
                *(bf16x4*)(base + (r * 1024 + ((512 + lane * 8) ^ swz))) = o;
            }
        }
    };
    auto loadB = [&](int t) {             // reload into same regs (1 tile ahead)
        if (t >= NTILES) return;
        int jbase = step_base + t * 16;
        #pragma unroll
        for (int ss = 0; ss < 4; ++ss) {
            int s = jbase + wave * 4 + ss;
            if (s > STEPS - 1) s = STEPS - 1;       // tail clamp (unconsumed)
            size_t off = (size_t)s * 512 + h * 128 + c * 8;
            bvr[ss] = *(const bf16x8*)(Bv + off);
            bcr[ss] = *(const bf16x8*)(Bc + off);
        }
    };
    auto compute = [&](int buf, int t) {
        const int nsteps = (t < 24) ? 16 : tail_steps;
        const char* base = (const char*)&lds[buf][0];
        const int swz = (c & 7) << 4;
        #pragma unroll
        for (int ss = 0; ss < 4; ++ss) {
            int s = wave * 4 + ss;
            if (s < nsteps) {
                bf16x8 a1 = *(const bf16x8*)(base + (c * 1024 + ((s * 64 + h * 16) ^ swz)));
                bf16x8 a2;
                #pragma unroll
                for (int i = 0; i < 8; ++i) {
                    float f = bf2f(a1[i]);
                    a2[i] = f2bf(f * f);
                }
                acc_s = __builtin_amdgcn_mfma_f32_16x16x32_bf16(a1, bvr[ss], acc_s, 0, 0, 0);
                acc_l = __builtin_amdgcn_mfma_f32_16x16x32_bf16(a1, bcr[ss], acc_l, 0, 0, 0);
                acc_q = __builtin_amdgcn_mfma_f32_16x16x32_bf16(a2, bcr[ss], acc_q, 0, 0, 0);
            }
        }
    };

    // prologue
    loadB(0);
    issue(0);
    writeLDS(0, 0);                       // waits tile-0 loads
    issue(1);
    // steady state: 1 barrier per tile
    for (int t = 0; t < NTILES; ++t) {
        __syncthreads();
        compute(t & 1, t);                // consumes B loaded a tile ago
        loadB(t + 1);                     // refill B regs (in flight ~1 tile)
        writeLDS((t + 1) & 1, t + 1);     // waits x(t+1); x(t+2) not yet issued
        issue(t + 2);
    }

    // epilogue: cross-wave k-partial reduction
    __syncthreads();
    float* red = (float*)&lds[0][0];      // 256 threads x 12 floats = 12KB
    int rbase = (wave * 64 + lane) * 12;
    #pragma unroll
    for (int i = 0; i < 4; ++i) {
        red[rbase + i]     = acc_s[i];
        red[rbase + 4 + i] = acc_l[i];
        red[rbase + 8 + i] = acc_q[i];
    }
    __syncthreads();
    if (wave == 0) {
        f32x4 s = {0,0,0,0}, l = {0,0,0,0}, q = {0,0,0,0};
        #pragma unroll
        for (int wv = 0; wv < 4; ++wv) {
            const float* rp = &red[(wv * 64 + lane) * 12];
            #pragma unroll
            for (int i = 0; i < 4; ++i) {
                s[i] += rp[i]; l[i] += rp[4 + i]; q[i] += rp[8 + i];
            }
        }
        // C/D layout: col = lane&15, row = (lane>>4)*4 + reg  [verified m89]
        #pragma unroll
        for (int r = 0; r < 4; ++r) {
            size_t row = (size_t)rowtile * 16 + h * 4 + r;
            float* Pp = P + (row * NSPLIT + split) * 18;
            Pp[c] = s[r];
            if (c == 0) Pp[16] = l[r];
            if (c == 1) Pp[17] = q[r];
        }
    }
}

// ---------------------------------------------------------------------------
// Kernel 3: reduce partials. One wave per batch row; lane = split (<8).
// out[b] = lin + 0.5*(sum_k s_k^2 - ss)
// ---------------------------------------------------------------------------
__global__ __launch_bounds__(64) void fm_reduce(const float* __restrict__ P,
                                                float* __restrict__ out) {
    int b = blockIdx.x;
    int lane = threadIdx.x;               // 0..63; splits 0..7 active
    float r[18];
    if (lane < NSPLIT) {
        const float* q = P + ((size_t)b * NSPLIT + lane) * 18;
        #pragma unroll
        for (int i = 0; i < 18; ++i) r[i] = q[i];
    } else {
        #pragma unroll
        for (int i = 0; i < 18; ++i) r[i] = 0.f;
    }
    #pragma unroll
    for (int off = 4; off > 0; off >>= 1) {
        #pragma unroll
        for (int i = 0; i < 18; ++i) r[i] += __shfl_xor(r[i], off, 64);
    }
    if (lane == 0) {
        float acc = r[16] - 0.5f * r[17];
        #pragma unroll
        for (int k = 0; k < 16; ++k) acc += 0.5f * r[k] * r[k];
        out[b] = acc;
    }
}

// ---------------------------------------------------------------------------
extern "C" void kernel_launch(void* const* d_in, const int* in_sizes, int n_in,
                              void* d_out, int out_size, void* d_ws, size_t ws_size,
                              hipStream_t stream) {
    const float* x = (const float*)d_in[0];   // [2048, 100000]
    const float* w = (const float*)d_in[1];   // [100000, 1]
    const float* v = (const float*)d_in[2];   // [100000, 16]
    float* out = (float*)d_out;               // [2048]

    char* ws = (char*)d_ws;
    short* Bv = (short*)(ws);                 // 3.2 MB
    short* Bc = (short*)(ws + 3200000);       // 3.2 MB
    float* P  = (float*)(ws + 6400000);       // 2048*8*18*4 = 1.18 MB

    fm_pack<<<(STEPS + 3) / 4, 256, 0, stream>>>(w, v, Bv, Bc);
    fm_main<<<NSPLIT * ROWTILES, 256, 0, stream>>>(x, Bv, Bc, P);
    fm_reduce<<<BATCH, 64, 0, stream>>>(P, out);
}